// Round 1
// baseline (572.427 us; speedup 1.0000x reference)
//
#include <hip/hip_runtime.h>
#include <hip/hip_bf16.h>
#include <math.h>

// Problem constants
#define BB   8
#define HI_  64
#define WI_  64
#define DD   128
#define HO_  32
#define WO_  32
#define NIN  4096
#define NOUT 1024
#define LN_EPS 1e-5f
#define ATT_EPS 1e-6f

// ---------------------------------------------------------------------------
// Tiled fp32 GEMM:  C[m][n] = sum_k A[m][k] * W[n][k]   (+bias, +gelu)
// AMODE: 0 = A row-major (lda), 1 = conv im2col gather from x (K=1152, tap-major)
// EPI:   0 = none, 1 = +bias, 2 = +bias then exact GELU
// REMAP: 0 = C row = m, 1 = unfold remap (fine pixel -> (b,head,coarse))
// Tile: BM=64, BN=64, BK=32, 256 threads, 4x4 per thread.
// ---------------------------------------------------------------------------
template<int AMODE, int EPI, int REMAP>
__global__ __launch_bounds__(256)
void gemm_kernel(const float* __restrict__ A, const float* __restrict__ W,
                 const float* __restrict__ bias, float* __restrict__ C,
                 int M, int N, int K, int lda)
{
    __shared__ float As[32][65];
    __shared__ float Ws[32][65];
    const int bm = blockIdx.x;
    const int bn = blockIdx.y;
    const int tid = threadIdx.x;
    const int tx = tid & 15, ty = tid >> 4;
    const int row0 = bm * 64, col0 = bn * 64;
    float acc[4][4] = {};

    for (int k0 = 0; k0 < K; k0 += 32) {
        #pragma unroll
        for (int i = 0; i < 8; ++i) {
            int idx = tid + i * 256;          // 0..2047
            int r = idx >> 5, c = idx & 31;   // tile row, tile k
            // ---- A element ----
            float av;
            int m = row0 + r;
            int kg = k0 + c;
            if (AMODE == 0) {
                av = A[(size_t)m * lda + kg];
            } else {
                // m -> (b, p(y,x)); kg -> (tap, di); input pixel (2y-1+ky, 2x-1+kx)
                int b = m >> 10, p = m & 1023;
                int y = p >> 5, x = p & 31;
                int tap = kg >> 7, di = kg & 127;
                int ky = tap / 3, kx = tap - ky * 3;
                int iy = 2 * y + ky - 1, ix = 2 * x + kx - 1;
                av = ((unsigned)iy < HI_ && (unsigned)ix < WI_)
                     ? A[((size_t)b * NIN + iy * WI_ + ix) * DD + di] : 0.f;
            }
            As[c][r] = av;
            // ---- W element (row-major N x K) ----
            Ws[c][r] = W[(size_t)(col0 + r) * K + (k0 + c)];
        }
        __syncthreads();
        #pragma unroll
        for (int kk = 0; kk < 32; ++kk) {
            float a[4], w[4];
            #pragma unroll
            for (int i = 0; i < 4; ++i) a[i] = As[kk][ty * 4 + i];
            #pragma unroll
            for (int j = 0; j < 4; ++j) w[j] = Ws[kk][tx * 4 + j];
            #pragma unroll
            for (int i = 0; i < 4; ++i)
                #pragma unroll
                for (int j = 0; j < 4; ++j)
                    acc[i][j] += a[i] * w[j];
        }
        __syncthreads();
    }

    #pragma unroll
    for (int i = 0; i < 4; ++i) {
        int m = row0 + ty * 4 + i;
        size_t orow;
        if (REMAP == 0) {
            orow = (size_t)m;
        } else {
            int b = m >> 12, pix = m & 4095;
            int iy = pix >> 6, ix = pix & 63;
            int h = ((iy & 1) << 1) | (ix & 1);
            int cp = ((iy >> 1) << 5) | (ix >> 1);
            orow = ((size_t)(b * 4 + h) << 10) + cp;
        }
        #pragma unroll
        for (int j = 0; j < 4; ++j) {
            int n = col0 + tx * 4 + j;
            float v = acc[i][j];
            if (EPI >= 1) v += bias[n];
            if (EPI == 2) v = 0.5f * v * (1.f + erff(v * 0.70710678118654752f));
            C[orow * N + n] = v;
        }
    }
}

// ---------------------------------------------------------------------------
// Per-row LayerNorm over D=128. ADD=0: out = LN(in); ADD=1: out += LN(in)
// ---------------------------------------------------------------------------
template<int ADD>
__global__ __launch_bounds__(128)
void ln_kernel(const float* __restrict__ in, const float* __restrict__ g,
               const float* __restrict__ bb, float* __restrict__ out)
{
    __shared__ float sbuf[2];
    const int row = blockIdx.x, tid = threadIdx.x;
    float v = in[(size_t)row * DD + tid];
    float s = v;
    #pragma unroll
    for (int o = 32; o > 0; o >>= 1) s += __shfl_down(s, o, 64);
    if ((tid & 63) == 0) sbuf[tid >> 6] = s;
    __syncthreads();
    float mu = (sbuf[0] + sbuf[1]) * (1.f / DD);
    __syncthreads();
    float d = v - mu;
    float s2 = d * d;
    #pragma unroll
    for (int o = 32; o > 0; o >>= 1) s2 += __shfl_down(s2, o, 64);
    if ((tid & 63) == 0) sbuf[tid >> 6] = s2;
    __syncthreads();
    float var = (sbuf[0] + sbuf[1]) * (1.f / DD);
    float y = d * (1.f / sqrtf(var + LN_EPS)) * g[tid] + bb[tid];
    if (ADD) out[(size_t)row * DD + tid] += y;
    else     out[(size_t)row * DD + tid] = y;
}

// ---------------------------------------------------------------------------
// Attention logits + softmax (+EPS).  One block per (b,p). 192 threads:
// 36 (h,jj) dots x 4 lanes each. Window slots use clamped NATTEN positions.
// sm layout: ((b*4+h)*1024 + p)*9 + jj
// ---------------------------------------------------------------------------
__global__ __launch_bounds__(192)
void attn_kernel(const float* __restrict__ q, const float* __restrict__ k,
                 const float* __restrict__ rpb, const float* __restrict__ tau,
                 float* __restrict__ sm)
{
    const int bp = blockIdx.x;
    const int b = bp >> 10, p = bp & 1023;
    const int cy = p >> 5, cx = p & 31;
    __shared__ __align__(16) float qs[DD];
    __shared__ float lg[36];
    const int tid = threadIdx.x;
    if (tid < DD) qs[tid] = q[(size_t)bp * DD + tid];
    __syncthreads();
    if (tid < 144) {
        int grp = tid >> 2, l = tid & 3;
        int h = grp / 9, jj = grp - h * 9;
        int ky = jj / 3, kx = jj - ky * 3;
        int ny = min(max(cy - 1, 0), HO_ - 3) + ky;
        int nx = min(max(cx - 1, 0), WO_ - 3) + kx;
        const float* kr = k + (((size_t)(b * 4 + h) << 10) + ny * WO_ + nx) * DD;
        float part = 0.f;
        #pragma unroll
        for (int i = 0; i < 8; ++i) {
            int d0 = (i * 4 + l) * 4;
            float4 kq = *reinterpret_cast<const float4*>(kr + d0);
            float4 qq = *reinterpret_cast<const float4*>(qs + d0);
            part += kq.x * qq.x + kq.y * qq.y + kq.z * qq.z + kq.w * qq.w;
        }
        part += __shfl_down(part, 1, 64);
        part += __shfl_down(part, 2, 64);
        if (l == 0) lg[grp] = part;
    }
    __syncthreads();
    if (tid < 4) {
        const int h = tid;
        float scale = expf(tau[0]);
        float tmp[9], mx = -1e30f;
        #pragma unroll
        for (int jj = 0; jj < 9; ++jj) {
            float v = (lg[h * 9 + jj] + rpb[h * 9 + jj]) * scale;
            tmp[jj] = v; mx = fmaxf(mx, v);
        }
        float ss = 0.f;
        #pragma unroll
        for (int jj = 0; jj < 9; ++jj) { tmp[jj] = expf(tmp[jj] - mx); ss += tmp[jj]; }
        float inv = 1.f / ss;
        float* dst = sm + (((size_t)(b * 4 + h) << 10) + p) * 9;
        #pragma unroll
        for (int jj = 0; jj < 9; ++jj) dst[jj] = tmp[jj] * inv + ATT_EPS;
    }
}

// ---------------------------------------------------------------------------
// Gather (centered-offset validity; invalid -> sm[b,h,0,0]) + denom + AV update.
// Also persists g and denom for the final A_row/A_col kernels.
// One block (128 threads) per (b,p).
// ---------------------------------------------------------------------------
__global__ __launch_bounds__(128)
void update_kernel(const float* __restrict__ sm, const float* __restrict__ v,
                   float* __restrict__ x_out, float* __restrict__ gbuf,
                   float* __restrict__ denom_buf)
{
    const int bp = blockIdx.x;
    const int b = bp >> 10, p = bp & 1023;
    const int cy = p >> 5, cx = p & 31;
    __shared__ float gs[36], coeff[36];
    __shared__ int nbrs[36];
    __shared__ float dsh;
    const int tid = threadIdx.x;
    if (tid < 36) {
        int h = tid / 9, jj = tid - h * 9;
        int dy = jj / 3 - 1, dx = jj % 3 - 1;
        bool valid = ((unsigned)(cy + dy) < HO_) && ((unsigned)(cx + dx) < WO_);
        size_t base = ((size_t)(b * 4 + h) << 10);
        float sval = valid ? sm[(base + p) * 9 + jj] : sm[base * 9 + 0];
        gs[tid] = sval;
        gbuf[(base + p) * 9 + jj] = sval;
        int ky = jj / 3, kx = jj % 3;
        int ny = min(max(cy - 1, 0), HO_ - 3) + ky;
        int nx = min(max(cx - 1, 0), WO_ - 3) + kx;
        nbrs[tid] = ny * WO_ + nx;
    }
    __syncthreads();
    if (tid == 0) {
        float s = 0.f;
        for (int i = 0; i < 36; ++i) s += gs[i];
        float df = 4.f * s + ATT_EPS;
        dsh = df;
        denom_buf[bp] = df;
    }
    __syncthreads();
    if (tid < 36) coeff[tid] = gs[tid] / dsh;
    __syncthreads();
    float acc = 0.f;
    #pragma unroll 4
    for (int t = 0; t < 36; ++t) {
        int h = t / 9;
        acc += coeff[t] * v[(((size_t)(b * 4 + h) << 10) + nbrs[t]) * DD + tid];
    }
    x_out[(size_t)bp * DD + tid] += acc;
}

// ---------------------------------------------------------------------------
// dump[b][jj] = (sum_h sm[b,h,0,0]) * sum_{p: offset jj invalid at p} 1/denom[b,p]
// ---------------------------------------------------------------------------
__global__ __launch_bounds__(64)
void dump_kernel(const float* __restrict__ sm, const float* __restrict__ denom,
                 float* __restrict__ dump)
{
    const int b = blockIdx.x;
    const int lane = threadIdx.x;
    float H = 0.f;
    if (lane == 0)
        for (int h = 0; h < 4; ++h)
            H += sm[(((size_t)(b * 4 + h) << 10)) * 9];
    for (int jj = 0; jj < 9; ++jj) {
        int dy = jj / 3 - 1, dx = jj % 3 - 1;
        float s = 0.f;
        for (int p = lane; p < NOUT; p += 64) {
            int cy = p >> 5, cx = p & 31;
            bool valid = ((unsigned)(cy + dy) < HO_) && ((unsigned)(cx + dx) < WO_);
            if (!valid) s += 1.f / denom[b * NOUT + p];
        }
        #pragma unroll
        for (int o = 32; o > 0; o >>= 1) s += __shfl_down(s, o, 64);
        if (lane == 0) dump[b * 9 + jj] = H * s;
    }
}

// ---------------------------------------------------------------------------
// A_row[b, h*1024+p, c]: 9 candidate cols (centered neighbor, invalid->0),
// each worth 4*g (the 4 tiled copies). Full row written once, no atomics.
// ---------------------------------------------------------------------------
__global__ __launch_bounds__(256)
void arow_kernel(const float* __restrict__ gbuf, float* __restrict__ Arow)
{
    const int bi = blockIdx.x;               // b*4096 + (h*1024+p)
    const int b = bi >> 12, i = bi & 4095;
    const int h = i >> 10, p = i & 1023;
    const int cy = p >> 5, cx = p & 31;
    __shared__ int cols[9];
    __shared__ float vals[9];
    const int tid = threadIdx.x;
    if (tid < 9) {
        int dy = tid / 3 - 1, dx = tid % 3 - 1;
        bool valid = ((unsigned)(cy + dy) < HO_) && ((unsigned)(cx + dx) < WO_);
        cols[tid] = valid ? (cy + dy) * WO_ + (cx + dx) : 0;
        vals[tid] = 4.f * gbuf[(((size_t)(b * 4 + h) << 10) + p) * 9 + tid];
    }
    __syncthreads();
    float* row = Arow + (size_t)bi * NOUT;
    #pragma unroll
    for (int cc = 0; cc < 4; ++cc) {
        int c = cc * 256 + tid;
        float acc = 0.f;
        #pragma unroll
        for (int jj = 0; jj < 9; ++jj)
            if (cols[jj] == c) acc += vals[jj];
        row[c] = acc;
    }
}

// ---------------------------------------------------------------------------
// A_col[b, r, j]: r = coarse*4 + h. For offset jj the unique source is
// p = coarse - (dy,dx) (if in bounds): value g[b,h,p,jj]/denom[b,p].
// Cols j = c*9+jj (4 identical copies); cols >=36 are zero.
// Row 0 additionally receives the invalid dump.
// ---------------------------------------------------------------------------
__global__ __launch_bounds__(256)
void acol_kernel(const float* __restrict__ gbuf, const float* __restrict__ denom,
                 const float* __restrict__ dump, float* __restrict__ Acol)
{
    const int br = blockIdx.x;               // b*4096 + r
    const int b = br >> 12, r = br & 4095;
    const int h = r & 3, coarse = r >> 2;
    const int cy = coarse >> 5, cx = coarse & 31;
    __shared__ float vals[9];
    const int tid = threadIdx.x;
    if (tid < 9) {
        int dy = tid / 3 - 1, dx = tid % 3 - 1;
        int py = cy - dy, px = cx - dx;
        float v = 0.f;
        if ((unsigned)py < HO_ && (unsigned)px < WO_) {
            int p = py * WO_ + px;
            v = gbuf[(((size_t)(b * 4 + h) << 10) + p) * 9 + tid]
                / denom[b * NOUT + p];
        }
        if (r == 0) v += dump[b * 9 + tid];
        vals[tid] = v;
    }
    __syncthreads();
    float* row = Acol + (size_t)br * NOUT;
    #pragma unroll
    for (int cc = 0; cc < 4; ++cc) {
        int c = cc * 256 + tid;
        row[c] = (c < 36) ? vals[c % 9] : 0.f;
    }
}

// ---------------------------------------------------------------------------
// seed_w (D,D,3,3) -> wconv[n][tap*128+di] (row-major N x 1152, tap-major K)
// ---------------------------------------------------------------------------
__global__ __launch_bounds__(256)
void wtrans_kernel(const float* __restrict__ sw, float* __restrict__ wc)
{
    int idx = blockIdx.x * 256 + threadIdx.x;       // total 147456
    if (idx < DD * DD * 9) {
        int n = idx / 1152;
        int rem = idx - n * 1152;
        int tap = rem >> 7, di = rem & 127;
        wc[idx] = sw[((size_t)(n * DD + di)) * 9 + tap];
    }
}

__global__ __launch_bounds__(256)
void copy_kernel(const float* __restrict__ src, float* __restrict__ dst, int n)
{
    int i = blockIdx.x * 256 + threadIdx.x;
    if (i < n) dst[i] = src[i];
}

// ---------------------------------------------------------------------------
extern "C" void kernel_launch(void* const* d_in, const int* in_sizes, int n_in,
                              void* d_out, int out_size, void* d_ws, size_t ws_size,
                              hipStream_t stream)
{
    const float* x        = (const float*)d_in[0];
    const float* seed_w   = (const float*)d_in[1];
    const float* wq       = (const float*)d_in[2];
    const float* wk       = (const float*)d_in[3];
    const float* wv       = (const float*)d_in[4];
    const float* w1       = (const float*)d_in[5];
    const float* b1       = (const float*)d_in[6];
    const float* w2       = (const float*)d_in[7];
    const float* b2       = (const float*)d_in[8];
    const float* ln_in_g  = (const float*)d_in[9];
    const float* ln_in_b  = (const float*)d_in[10];
    const float* ln_out_g = (const float*)d_in[11];
    const float* ln_out_b = (const float*)d_in[12];
    const float* rpb      = (const float*)d_in[13];
    const float* tau      = (const float*)d_in[14];

    float* out  = (float*)d_out;
    float* Arow = out + (size_t)BB * NOUT * DD;        // 1,048,576
    float* Acol = Arow + (size_t)BB * NIN * NOUT;      // +33,554,432

    // Small, must-survive scratch in d_ws (~6 MB):
    float* ws    = (float*)d_ws;
    float* xout  = ws;                       // 1,048,576  (evolving state)
    float* gbuf  = xout + (size_t)BB * NOUT * DD;      // 294,912
    float* denb  = gbuf + (size_t)BB * 4 * NOUT * 9;   // 8,192
    float* dumpb = denb + BB * NOUT;                   // 72
    float* wconv = dumpb + 128;                        // 147,456

    // Big dead-by-the-end scratch carved from the A_row output region (128 MB):
    float* lnx  = Arow;                                 // 4,194,304
    float* kbuf = lnx  + (size_t)BB * NIN * DD;         // 4,194,304
    float* vbuf = kbuf + (size_t)BB * NIN * DD;         // 4,194,304
    float* h1   = vbuf + (size_t)BB * NIN * DD;         // 2,097,152
    float* lnq  = h1   + (size_t)BB * NOUT * 2 * DD;    // 1,048,576
    float* qb   = lnq  + (size_t)BB * NOUT * DD;        // 1,048,576
    float* tmp  = qb   + (size_t)BB * NOUT * DD;        // 1,048,576
    float* smb  = tmp  + (size_t)BB * NOUT * DD;        // 294,912  (raw softmax)

    // --- preamble ---
    wtrans_kernel<<<(DD * DD * 9 + 255) / 256, 256, 0, stream>>>(seed_w, wconv);
    ln_kernel<0><<<BB * NIN, 128, 0, stream>>>(x, ln_in_g, ln_in_b, lnx);
    gemm_kernel<0, 0, 1><<<dim3(BB * NIN / 64, 2), 256, 0, stream>>>(
        lnx, wk, nullptr, kbuf, BB * NIN, DD, DD, DD);
    gemm_kernel<0, 0, 1><<<dim3(BB * NIN / 64, 2), 256, 0, stream>>>(
        x, wv, nullptr, vbuf, BB * NIN, DD, DD, DD);
    gemm_kernel<1, 0, 0><<<dim3(BB * NOUT / 64, 2), 256, 0, stream>>>(
        x, wconv, nullptr, tmp, BB * NOUT, DD, 1152, 0);
    ln_kernel<0><<<BB * NOUT, 128, 0, stream>>>(tmp, ln_out_g, ln_out_b, xout);

    // --- 3 iterations ---
    for (int it = 0; it < 3; ++it) {
        ln_kernel<0><<<BB * NOUT, 128, 0, stream>>>(xout, ln_out_g, ln_out_b, lnq);
        gemm_kernel<0, 0, 0><<<dim3(BB * NOUT / 64, 2), 256, 0, stream>>>(
            lnq, wq, nullptr, qb, BB * NOUT, DD, DD, DD);
        attn_kernel<<<BB * NOUT, 192, 0, stream>>>(qb, kbuf, rpb, tau, smb);
        update_kernel<<<BB * NOUT, 128, 0, stream>>>(smb, vbuf, xout, gbuf, denb);
        gemm_kernel<0, 2, 0><<<dim3(BB * NOUT / 64, 4), 256, 0, stream>>>(
            xout, w1, b1, h1, BB * NOUT, 2 * DD, DD, DD);
        gemm_kernel<0, 1, 0><<<dim3(BB * NOUT / 64, 2), 256, 0, stream>>>(
            h1, w2, b2, tmp, BB * NOUT, DD, 2 * DD, 2 * DD);
        ln_kernel<1><<<BB * NOUT, 128, 0, stream>>>(tmp, ln_out_g, ln_out_b, xout);
    }

    // --- epilogue: dump sums, x_out, A_row, A_col ---
    dump_kernel<<<BB, 64, 0, stream>>>(smb, denb, dumpb);
    copy_kernel<<<(BB * NOUT * DD + 255) / 256, 256, 0, stream>>>(
        xout, out, BB * NOUT * DD);
    arow_kernel<<<BB * NIN, 256, 0, stream>>>(gbuf, Arow);
    acol_kernel<<<BB * NIN, 256, 0, stream>>>(gbuf, denb, dumpb, Acol);
}

// Round 2
// 371.144 us; speedup vs baseline: 1.5423x; 1.5423x over previous
//
#include <hip/hip_runtime.h>
#include <hip/hip_bf16.h>
#include <math.h>

// Problem constants
#define BB   8
#define HI_  64
#define WI_  64
#define DD   128
#define HO_  32
#define WO_  32
#define NIN  4096
#define NOUT 1024
#define LN_EPS 1e-5f
#define ATT_EPS 1e-6f

typedef short bf16x8 __attribute__((ext_vector_type(8)));
typedef float f32x4  __attribute__((ext_vector_type(4)));

__device__ __forceinline__ ushort f2bf(float f) {
    union { float f; unsigned u; } a; a.f = f;
    unsigned u = a.u;
    return (ushort)((u + 0x7FFFu + ((u >> 16) & 1u)) >> 16);
}

// ---------------------------------------------------------------------------
// bf16 MFMA GEMM:  C[m][n] = sum_k A[m][k] * W[n][k]   (+bias, +gelu)
// A fp32 (converted to bf16 in staging), W bf16 (pre-converted, N x K row-major).
// AMODE: 0 = A row-major (lda), 1 = conv im2col gather from x (K=1152, tap-major)
// EPI:   0 = none, 1 = +bias, 2 = +bias then exact GELU
// REMAP: 0 = C row = m, 1 = unfold remap (fine pixel -> (b,head,coarse))
// Tile: BM=64, BN=64, BK=64; 256 threads = 4 waves, each wave 32x32 output.
// ---------------------------------------------------------------------------
template<int AMODE, int EPI, int REMAP>
__global__ __launch_bounds__(256)
void mgemm_kernel(const float* __restrict__ A, const ushort* __restrict__ W,
                  const float* __restrict__ bias, float* __restrict__ C,
                  int N, int K, int lda)
{
    __shared__ ushort As[64][72];   // 72-pad: stride 144B, even bank spread
    __shared__ ushort Bs[64][72];
    const int tid  = threadIdx.x;
    const int wid  = tid >> 6, lane = tid & 63;
    const int row0 = blockIdx.x * 64, col0 = blockIdx.y * 64;
    const int wm = (wid & 1) * 32, wn = (wid >> 1) * 32;
    const int lr = lane & 15;            // fragment row (M for A, N for B)
    const int lk = (lane >> 4) << 3;     // fragment k-offset (8 bf16)
    f32x4 acc[2][2] = {};

    for (int k0 = 0; k0 < K; k0 += 64) {
        // ---- stage A: 64 rows x 64 k, fp32 -> bf16 ----
        #pragma unroll
        for (int i = 0; i < 4; ++i) {
            int linear = tid + (i << 8);          // float4 id, 1024 total
            int r = linear >> 4, c4 = (linear & 15) << 2;
            float4 v;
            if (AMODE == 0) {
                v = *reinterpret_cast<const float4*>(A + (size_t)(row0 + r) * lda + k0 + c4);
            } else {
                int m = row0 + r;
                int b = m >> 10, p = m & 1023;
                int y = p >> 5, xx = p & 31;
                int kg = k0 + c4;
                int tap = kg >> 7, di = kg & 127;
                int ky = tap / 3, kx = tap - ky * 3;
                int iy = 2 * y + ky - 1, ix = 2 * xx + kx - 1;
                if ((unsigned)iy < (unsigned)HI_ && (unsigned)ix < (unsigned)WI_)
                    v = *reinterpret_cast<const float4*>(
                        A + ((size_t)b * NIN + iy * WI_ + ix) * DD + di);
                else
                    v = make_float4(0.f, 0.f, 0.f, 0.f);
            }
            ushort4 o;
            o.x = f2bf(v.x); o.y = f2bf(v.y); o.z = f2bf(v.z); o.w = f2bf(v.w);
            *reinterpret_cast<ushort4*>(&As[r][c4]) = o;
        }
        // ---- stage B: 64 rows x 64 k bf16 (16B per thread-load) ----
        #pragma unroll
        for (int i = 0; i < 2; ++i) {
            int linear = tid + (i << 8);          // 8-elem id, 512 total
            int r = linear >> 3, c8 = (linear & 7) << 3;
            *reinterpret_cast<uint4*>(&Bs[r][c8]) =
                *reinterpret_cast<const uint4*>(W + (size_t)(col0 + r) * K + k0 + c8);
        }
        __syncthreads();
        // ---- compute: 2 k-steps of 32 ----
        #pragma unroll
        for (int ks = 0; ks < 2; ++ks) {
            const int kk = (ks << 5) + lk;
            bf16x8 af0 = *reinterpret_cast<const bf16x8*>(&As[wm + lr][kk]);
            bf16x8 af1 = *reinterpret_cast<const bf16x8*>(&As[wm + 16 + lr][kk]);
            bf16x8 bf0 = *reinterpret_cast<const bf16x8*>(&Bs[wn + lr][kk]);
            bf16x8 bf1 = *reinterpret_cast<const bf16x8*>(&Bs[wn + 16 + lr][kk]);
            acc[0][0] = __builtin_amdgcn_mfma_f32_16x16x32_bf16(af0, bf0, acc[0][0], 0, 0, 0);
            acc[0][1] = __builtin_amdgcn_mfma_f32_16x16x32_bf16(af0, bf1, acc[0][1], 0, 0, 0);
            acc[1][0] = __builtin_amdgcn_mfma_f32_16x16x32_bf16(af1, bf0, acc[1][0], 0, 0, 0);
            acc[1][1] = __builtin_amdgcn_mfma_f32_16x16x32_bf16(af1, bf1, acc[1][1], 0, 0, 0);
        }
        __syncthreads();
    }

    // ---- epilogue: C/D layout col=lane&15, row=(lane>>4)*4+reg ----
    #pragma unroll
    for (int mi = 0; mi < 2; ++mi) {
        const int mbase = row0 + wm + mi * 16 + ((lane >> 4) << 2);
        #pragma unroll
        for (int ni = 0; ni < 2; ++ni) {
            const int n = col0 + wn + ni * 16 + (lane & 15);
            const float bv = (EPI >= 1) ? bias[n] : 0.f;
            #pragma unroll
            for (int r = 0; r < 4; ++r) {
                int m = mbase + r;
                float v = acc[mi][ni][r] + bv;
                if (EPI == 2) v = 0.5f * v * (1.f + erff(v * 0.70710678118654752f));
                size_t orow;
                if (REMAP == 0) {
                    orow = (size_t)m;
                } else {
                    int b = m >> 12, pix = m & 4095;
                    int iy = pix >> 6, ix = pix & 63;
                    int h = ((iy & 1) << 1) | (ix & 1);
                    int cp = ((iy >> 1) << 5) | (ix >> 1);
                    orow = ((size_t)(b * 4 + h) << 10) + cp;
                }
                C[orow * N + n] = v;
            }
        }
    }
}

// ---------------------------------------------------------------------------
// Fused weight conversion to bf16 (+ conv weight transpose to tap-major N x K).
// Layout in dst: [wk 16384][wv 16384][wq 16384][w1 32768][w2 32768][wc 147456]
// ---------------------------------------------------------------------------
__global__ __launch_bounds__(256)
void wconvert_kernel(const float* __restrict__ wq, const float* __restrict__ wk,
                     const float* __restrict__ wv, const float* __restrict__ w1,
                     const float* __restrict__ w2, const float* __restrict__ sw,
                     ushort* __restrict__ dst)
{
    int i = blockIdx.x * 256 + threadIdx.x;   // total 262144
    float v;
    if (i < 16384)        v = wk[i];
    else if (i < 32768)   v = wv[i - 16384];
    else if (i < 49152)   v = wq[i - 32768];
    else if (i < 81920)   v = w1[i - 49152];
    else if (i < 114688)  v = w2[i - 81920];
    else {
        int j = i - 114688;
        int n = j / 1152;
        int rem = j - n * 1152;
        int tap = rem >> 7, di = rem & 127;
        v = sw[((size_t)(n * DD + di)) * 9 + tap];
    }
    dst[i] = f2bf(v);
}

// ---------------------------------------------------------------------------
// Per-row LayerNorm over D=128. ADD=0: out = LN(in); ADD=1: out += LN(in)
// ---------------------------------------------------------------------------
template<int ADD>
__global__ __launch_bounds__(128)
void ln_kernel(const float* __restrict__ in, const float* __restrict__ g,
               const float* __restrict__ bb, float* __restrict__ out)
{
    __shared__ float sbuf[2];
    const int row = blockIdx.x, tid = threadIdx.x;
    float v = in[(size_t)row * DD + tid];
    float s = v;
    #pragma unroll
    for (int o = 32; o > 0; o >>= 1) s += __shfl_down(s, o, 64);
    if ((tid & 63) == 0) sbuf[tid >> 6] = s;
    __syncthreads();
    float mu = (sbuf[0] + sbuf[1]) * (1.f / DD);
    __syncthreads();
    float d = v - mu;
    float s2 = d * d;
    #pragma unroll
    for (int o = 32; o > 0; o >>= 1) s2 += __shfl_down(s2, o, 64);
    if ((tid & 63) == 0) sbuf[tid >> 6] = s2;
    __syncthreads();
    float var = (sbuf[0] + sbuf[1]) * (1.f / DD);
    float y = d * (1.f / sqrtf(var + LN_EPS)) * g[tid] + bb[tid];
    if (ADD) out[(size_t)row * DD + tid] += y;
    else     out[(size_t)row * DD + tid] = y;
}

// ---------------------------------------------------------------------------
// Attention logits + softmax (+EPS).  One block per (b,p). 192 threads:
// 36 (h,jj) dots x 4 lanes each. Window slots use clamped NATTEN positions.
// sm layout: ((b*4+h)*1024 + p)*9 + jj
// ---------------------------------------------------------------------------
__global__ __launch_bounds__(192)
void attn_kernel(const float* __restrict__ q, const float* __restrict__ k,
                 const float* __restrict__ rpb, const float* __restrict__ tau,
                 float* __restrict__ sm)
{
    const int bp = blockIdx.x;
    const int b = bp >> 10, p = bp & 1023;
    const int cy = p >> 5, cx = p & 31;
    __shared__ __align__(16) float qs[DD];
    __shared__ float lg[36];
    const int tid = threadIdx.x;
    if (tid < DD) qs[tid] = q[(size_t)bp * DD + tid];
    __syncthreads();
    if (tid < 144) {
        int grp = tid >> 2, l = tid & 3;
        int h = grp / 9, jj = grp - h * 9;
        int ky = jj / 3, kx = jj - ky * 3;
        int ny = min(max(cy - 1, 0), HO_ - 3) + ky;
        int nx = min(max(cx - 1, 0), WO_ - 3) + kx;
        const float* kr = k + (((size_t)(b * 4 + h) << 10) + ny * WO_ + nx) * DD;
        float part = 0.f;
        #pragma unroll
        for (int i = 0; i < 8; ++i) {
            int d0 = (i * 4 + l) * 4;
            float4 kq = *reinterpret_cast<const float4*>(kr + d0);
            float4 qq = *reinterpret_cast<const float4*>(qs + d0);
            part += kq.x * qq.x + kq.y * qq.y + kq.z * qq.z + kq.w * qq.w;
        }
        part += __shfl_down(part, 1, 64);
        part += __shfl_down(part, 2, 64);
        if (l == 0) lg[grp] = part;
    }
    __syncthreads();
    if (tid < 4) {
        const int h = tid;
        float scale = expf(tau[0]);
        float tmp[9], mx = -1e30f;
        #pragma unroll
        for (int jj = 0; jj < 9; ++jj) {
            float v = (lg[h * 9 + jj] + rpb[h * 9 + jj]) * scale;
            tmp[jj] = v; mx = fmaxf(mx, v);
        }
        float ss = 0.f;
        #pragma unroll
        for (int jj = 0; jj < 9; ++jj) { tmp[jj] = expf(tmp[jj] - mx); ss += tmp[jj]; }
        float inv = 1.f / ss;
        float* dst = sm + (((size_t)(b * 4 + h) << 10) + p) * 9;
        #pragma unroll
        for (int jj = 0; jj < 9; ++jj) dst[jj] = tmp[jj] * inv + ATT_EPS;
    }
}

// ---------------------------------------------------------------------------
// Gather (centered-offset validity; invalid -> sm[b,h,0,0]) + denom + AV update.
// Also persists g and denom for the final A_row/A_col kernels.
// One block (128 threads) per (b,p).
// ---------------------------------------------------------------------------
__global__ __launch_bounds__(128)
void update_kernel(const float* __restrict__ sm, const float* __restrict__ v,
                   float* __restrict__ x_out, float* __restrict__ gbuf,
                   float* __restrict__ denom_buf)
{
    const int bp = blockIdx.x;
    const int b = bp >> 10, p = bp & 1023;
    const int cy = p >> 5, cx = p & 31;
    __shared__ float gs[36], coeff[36];
    __shared__ int nbrs[36];
    __shared__ float dsh;
    const int tid = threadIdx.x;
    if (tid < 36) {
        int h = tid / 9, jj = tid - h * 9;
        int dy = jj / 3 - 1, dx = jj % 3 - 1;
        bool valid = ((unsigned)(cy + dy) < HO_) && ((unsigned)(cx + dx) < WO_);
        size_t base = ((size_t)(b * 4 + h) << 10);
        float sval = valid ? sm[(base + p) * 9 + jj] : sm[base * 9 + 0];
        gs[tid] = sval;
        gbuf[(base + p) * 9 + jj] = sval;
        int ky = jj / 3, kx = jj % 3;
        int ny = min(max(cy - 1, 0), HO_ - 3) + ky;
        int nx = min(max(cx - 1, 0), WO_ - 3) + kx;
        nbrs[tid] = ny * WO_ + nx;
    }
    __syncthreads();
    if (tid == 0) {
        float s = 0.f;
        for (int i = 0; i < 36; ++i) s += gs[i];
        float df = 4.f * s + ATT_EPS;
        dsh = df;
        denom_buf[bp] = df;
    }
    __syncthreads();
    if (tid < 36) coeff[tid] = gs[tid] / dsh;
    __syncthreads();
    float acc = 0.f;
    #pragma unroll 4
    for (int t = 0; t < 36; ++t) {
        int h = t / 9;
        acc += coeff[t] * v[(((size_t)(b * 4 + h) << 10) + nbrs[t]) * DD + tid];
    }
    x_out[(size_t)bp * DD + tid] += acc;
}

// ---------------------------------------------------------------------------
// dump[b][jj] = (sum_h sm[b,h,0,0]) * sum_{p: offset jj invalid at p} 1/denom[b,p]
// ---------------------------------------------------------------------------
__global__ __launch_bounds__(64)
void dump_kernel(const float* __restrict__ sm, const float* __restrict__ denom,
                 float* __restrict__ dump)
{
    const int b = blockIdx.x;
    const int lane = threadIdx.x;
    float H = 0.f;
    if (lane == 0)
        for (int h = 0; h < 4; ++h)
            H += sm[(((size_t)(b * 4 + h) << 10)) * 9];
    for (int jj = 0; jj < 9; ++jj) {
        int dy = jj / 3 - 1, dx = jj % 3 - 1;
        float s = 0.f;
        for (int p = lane; p < NOUT; p += 64) {
            int cy = p >> 5, cx = p & 31;
            bool valid = ((unsigned)(cy + dy) < HO_) && ((unsigned)(cx + dx) < WO_);
            if (!valid) s += 1.f / denom[b * NOUT + p];
        }
        #pragma unroll
        for (int o = 32; o > 0; o >>= 1) s += __shfl_down(s, o, 64);
        if (lane == 0) dump[b * 9 + jj] = H * s;
    }
}

// ---------------------------------------------------------------------------
// A_row[b, h*1024+p, c]: 9 candidate cols (centered neighbor, invalid->0),
// each worth 4*g (the 4 tiled copies). Full row written once, no atomics.
// ---------------------------------------------------------------------------
__global__ __launch_bounds__(256)
void arow_kernel(const float* __restrict__ gbuf, float* __restrict__ Arow)
{
    const int bi = blockIdx.x;               // b*4096 + (h*1024+p)
    const int b = bi >> 12, i = bi & 4095;
    const int h = i >> 10, p = i & 1023;
    const int cy = p >> 5, cx = p & 31;
    __shared__ int cols[9];
    __shared__ float vals[9];
    const int tid = threadIdx.x;
    if (tid < 9) {
        int dy = tid / 3 - 1, dx = tid % 3 - 1;
        bool valid = ((unsigned)(cy + dy) < HO_) && ((unsigned)(cx + dx) < WO_);
        cols[tid] = valid ? (cy + dy) * WO_ + (cx + dx) : 0;
        vals[tid] = 4.f * gbuf[(((size_t)(b * 4 + h) << 10) + p) * 9 + tid];
    }
    __syncthreads();
    float* row = Arow + (size_t)bi * NOUT;
    #pragma unroll
    for (int cc = 0; cc < 4; ++cc) {
        int c = cc * 256 + tid;
        float acc = 0.f;
        #pragma unroll
        for (int jj = 0; jj < 9; ++jj)
            if (cols[jj] == c) acc += vals[jj];
        row[c] = acc;
    }
}

// ---------------------------------------------------------------------------
// A_col[b, r, j]: r = coarse*4 + h. For offset jj the unique source is
// p = coarse - (dy,dx) (if in bounds): value g[b,h,p,jj]/denom[b,p].
// Cols j = c*9+jj (4 identical copies); cols >=36 are zero.
// Row 0 additionally receives the invalid dump.
// ---------------------------------------------------------------------------
__global__ __launch_bounds__(256)
void acol_kernel(const float* __restrict__ gbuf, const float* __restrict__ denom,
                 const float* __restrict__ dump, float* __restrict__ Acol)
{
    const int br = blockIdx.x;               // b*4096 + r
    const int b = br >> 12, r = br & 4095;
    const int h = r & 3, coarse = r >> 2;
    const int cy = coarse >> 5, cx = coarse & 31;
    __shared__ float vals[9];
    const int tid = threadIdx.x;
    if (tid < 9) {
        int dy = tid / 3 - 1, dx = tid % 3 - 1;
        int py = cy - dy, px = cx - dx;
        float v = 0.f;
        if ((unsigned)py < HO_ && (unsigned)px < WO_) {
            int p = py * WO_ + px;
            v = gbuf[(((size_t)(b * 4 + h) << 10) + p) * 9 + tid]
                / denom[b * NOUT + p];
        }
        if (r == 0) v += dump[b * 9 + tid];
        vals[tid] = v;
    }
    __syncthreads();
    float* row = Acol + (size_t)br * NOUT;
    #pragma unroll
    for (int cc = 0; cc < 4; ++cc) {
        int c = cc * 256 + tid;
        row[c] = (c < 36) ? vals[c % 9] : 0.f;
    }
}

__global__ __launch_bounds__(256)
void copy_kernel(const float* __restrict__ src, float* __restrict__ dst, int n)
{
    int i = blockIdx.x * 256 + threadIdx.x;
    if (i < n) dst[i] = src[i];
}

// ---------------------------------------------------------------------------
extern "C" void kernel_launch(void* const* d_in, const int* in_sizes, int n_in,
                              void* d_out, int out_size, void* d_ws, size_t ws_size,
                              hipStream_t stream)
{
    const float* x        = (const float*)d_in[0];
    const float* seed_w   = (const float*)d_in[1];
    const float* wq       = (const float*)d_in[2];
    const float* wk       = (const float*)d_in[3];
    const float* wv       = (const float*)d_in[4];
    const float* w1       = (const float*)d_in[5];
    const float* b1       = (const float*)d_in[6];
    const float* w2       = (const float*)d_in[7];
    const float* b2       = (const float*)d_in[8];
    const float* ln_in_g  = (const float*)d_in[9];
    const float* ln_in_b  = (const float*)d_in[10];
    const float* ln_out_g = (const float*)d_in[11];
    const float* ln_out_b = (const float*)d_in[12];
    const float* rpb      = (const float*)d_in[13];
    const float* tau      = (const float*)d_in[14];

    float* out  = (float*)d_out;
    float* Arow = out + (size_t)BB * NOUT * DD;        // 1,048,576
    float* Acol = Arow + (size_t)BB * NIN * NOUT;      // +33,554,432

    // Small, must-survive scratch in d_ws (~6.3 MB):
    float* ws    = (float*)d_ws;
    float* xout  = ws;                                 // 1,048,576
    float* gbuf  = xout + (size_t)BB * NOUT * DD;      // 294,912
    float* denb  = gbuf + (size_t)BB * 4 * NOUT * 9;   // 8,192
    float* dumpb = denb + BB * NOUT;                   // 72 (+pad)
    ushort* wb   = (ushort*)(dumpb + 128);             // 262,144 ushorts
    ushort* wkb  = wb;
    ushort* wvb  = wb + 16384;
    ushort* wqb  = wb + 32768;
    ushort* w1b  = wb + 49152;
    ushort* w2b  = wb + 81920;
    ushort* wcb  = wb + 114688;

    // Big dead-by-the-end scratch carved from the A_row output region (128 MB):
    float* lnx  = Arow;                                 // 4,194,304
    float* kbuf = lnx  + (size_t)BB * NIN * DD;         // 4,194,304
    float* vbuf = kbuf + (size_t)BB * NIN * DD;         // 4,194,304
    float* h1   = vbuf + (size_t)BB * NIN * DD;         // 2,097,152
    float* lnq  = h1   + (size_t)BB * NOUT * 2 * DD;    // 1,048,576
    float* qb   = lnq  + (size_t)BB * NOUT * DD;        // 1,048,576
    float* tmp  = qb   + (size_t)BB * NOUT * DD;        // 1,048,576
    float* smb  = tmp  + (size_t)BB * NOUT * DD;        // 294,912  (raw softmax)

    // --- preamble ---
    wconvert_kernel<<<1024, 256, 0, stream>>>(wq, wk, wv, w1, w2, seed_w, wb);
    ln_kernel<0><<<BB * NIN, 128, 0, stream>>>(x, ln_in_g, ln_in_b, lnx);
    mgemm_kernel<0, 0, 1><<<dim3(BB * NIN / 64, 2), 256, 0, stream>>>(
        lnx, wkb, nullptr, kbuf, DD, DD, DD);
    mgemm_kernel<0, 0, 1><<<dim3(BB * NIN / 64, 2), 256, 0, stream>>>(
        x, wvb, nullptr, vbuf, DD, DD, DD);
    mgemm_kernel<1, 0, 0><<<dim3(BB * NOUT / 64, 2), 256, 0, stream>>>(
        x, wcb, nullptr, tmp, DD, 1152, 0);
    ln_kernel<0><<<BB * NOUT, 128, 0, stream>>>(tmp, ln_out_g, ln_out_b, xout);

    // --- 3 iterations ---
    for (int it = 0; it < 3; ++it) {
        ln_kernel<0><<<BB * NOUT, 128, 0, stream>>>(xout, ln_out_g, ln_out_b, lnq);
        mgemm_kernel<0, 0, 0><<<dim3(BB * NOUT / 64, 2), 256, 0, stream>>>(
            lnq, wqb, nullptr, qb, DD, DD, DD);
        attn_kernel<<<BB * NOUT, 192, 0, stream>>>(qb, kbuf, rpb, tau, smb);
        update_kernel<<<BB * NOUT, 128, 0, stream>>>(smb, vbuf, xout, gbuf, denb);
        mgemm_kernel<0, 2, 0><<<dim3(BB * NOUT / 64, 4), 256, 0, stream>>>(
            xout, w1b, b1, h1, 2 * DD, DD, DD);
        mgemm_kernel<0, 1, 0><<<dim3(BB * NOUT / 64, 2), 256, 0, stream>>>(
            h1, w2b, b2, tmp, DD, 2 * DD, 2 * DD);
        ln_kernel<1><<<BB * NOUT, 128, 0, stream>>>(tmp, ln_out_g, ln_out_b, xout);
    }

    // --- epilogue: dump sums, x_out, A_row, A_col ---
    dump_kernel<<<BB, 64, 0, stream>>>(smb, denb, dumpb);
    copy_kernel<<<(BB * NOUT * DD + 255) / 256, 256, 0, stream>>>(
        xout, out, BB * NOUT * DD);
    arow_kernel<<<BB * NIN, 256, 0, stream>>>(gbuf, Arow);
    acol_kernel<<<BB * NIN, 256, 0, stream>>>(gbuf, denb, dumpb, Acol);
}

// Round 4
// 223.029 us; speedup vs baseline: 2.5666x; 1.6641x over previous
//
#include <hip/hip_runtime.h>
#include <hip/hip_bf16.h>
#include <math.h>

// Problem constants
#define BB   8
#define HI_  64
#define WI_  64
#define DD   128
#define HO_  32
#define WO_  32
#define NIN  4096
#define NOUT 1024
#define LN_EPS 1e-5f
#define ATT_EPS 1e-6f

typedef short bf16x8 __attribute__((ext_vector_type(8)));
typedef float f32x4  __attribute__((ext_vector_type(4)));

__device__ __forceinline__ ushort f2bf(float f) {
    union { float f; unsigned u; } a; a.f = f;
    unsigned u = a.u;
    return (ushort)((u + 0x7FFFu + ((u >> 16) & 1u)) >> 16);
}
__device__ __forceinline__ float bf2f(ushort u) {
    union { unsigned u; float f; } a; a.u = ((unsigned)u) << 16;
    return a.f;
}

// ---------------------------------------------------------------------------
// Weight conversion to bf16 (+ conv weight transpose to tap-major N x K).
// Layout: [wk 16384][wv 16384][wq 16384][w1 32768][w2 32768][wc 147456]
// ---------------------------------------------------------------------------
__global__ __launch_bounds__(256)
void wconvert_kernel(const float* __restrict__ wq, const float* __restrict__ wk,
                     const float* __restrict__ wv, const float* __restrict__ w1,
                     const float* __restrict__ w2, const float* __restrict__ sw,
                     ushort* __restrict__ dst)
{
    int i = blockIdx.x * 256 + threadIdx.x;   // total 262144
    float v;
    if (i < 16384)        v = wk[i];
    else if (i < 32768)   v = wv[i - 16384];
    else if (i < 49152)   v = wq[i - 32768];
    else if (i < 81920)   v = w1[i - 49152];
    else if (i < 114688)  v = w2[i - 81920];
    else {
        int j = i - 114688;
        int n = j / 1152;
        int rem = j - n * 1152;
        int tap = rem >> 7, di = rem & 127;
        v = sw[((size_t)(n * DD + di)) * 9 + tap];
    }
    dst[i] = f2bf(v);
}

// ---------------------------------------------------------------------------
// prep_kv: per 64-row block of x: LN(x) -> k GEMM, x -> v GEMM, write bf16
// kbuf/vbuf with unfold remap. K=128 single-shot. 4 waves (2M x 2N, 32x64).
// ---------------------------------------------------------------------------
__global__ __launch_bounds__(256)
void prep_kv_kernel(const float* __restrict__ x, const ushort* __restrict__ wkb,
                    const ushort* __restrict__ wvb,
                    const float* __restrict__ lg_, const float* __restrict__ lb_,
                    ushort* __restrict__ kbuf, ushort* __restrict__ vbuf)
{
    __shared__ float  xs[64][132];
    __shared__ ushort Aln[64][136];
    __shared__ ushort Araw[64][136];
    __shared__ ushort Bk[128][136];
    __shared__ ushort Bv[128][136];
    __shared__ float  rstat[64][2];
    const int tid = threadIdx.x;
    const int row0 = blockIdx.x * 64;

    #pragma unroll
    for (int i = 0; i < 8; ++i) {               // 2048 float4
        int l = tid + i * 256;
        int r = l >> 5, c4 = (l & 31) << 2;
        float4 v = *(const float4*)(x + (size_t)(row0 + r) * DD + c4);
        *(float4*)&xs[r][c4] = v;
        ushort4 o; o.x = f2bf(v.x); o.y = f2bf(v.y); o.z = f2bf(v.z); o.w = f2bf(v.w);
        *(ushort4*)&Araw[r][c4] = o;
    }
    __syncthreads();
    {   // row stats: 4 threads/row
        int r = tid >> 2, q = tid & 3;
        float s = 0.f, s2 = 0.f;
        #pragma unroll
        for (int c = 0; c < 32; ++c) { float v = xs[r][q * 32 + c]; s += v; s2 += v * v; }
        s += __shfl_down(s, 1, 64); s2 += __shfl_down(s2, 1, 64);
        s += __shfl_down(s, 2, 64); s2 += __shfl_down(s2, 2, 64);
        if (q == 0) {
            float mu = s * (1.f / DD);
            float var = s2 * (1.f / DD) - mu * mu;
            rstat[r][0] = mu; rstat[r][1] = rsqrtf(var + LN_EPS);
        }
    }
    __syncthreads();
    #pragma unroll
    for (int i = 0; i < 8; ++i) {               // build Aln
        int l = tid + i * 256;
        int r = l >> 5, c4 = (l & 31) << 2;
        float mu = rstat[r][0], rs = rstat[r][1];
        ushort4 o;
        o.x = f2bf((xs[r][c4 + 0] - mu) * rs * lg_[c4 + 0] + lb_[c4 + 0]);
        o.y = f2bf((xs[r][c4 + 1] - mu) * rs * lg_[c4 + 1] + lb_[c4 + 1]);
        o.z = f2bf((xs[r][c4 + 2] - mu) * rs * lg_[c4 + 2] + lb_[c4 + 2]);
        o.w = f2bf((xs[r][c4 + 3] - mu) * rs * lg_[c4 + 3] + lb_[c4 + 3]);
        *(ushort4*)&Aln[r][c4] = o;
    }
    #pragma unroll
    for (int i = 0; i < 8; ++i) {               // weights: 2048 uint4 each
        int l = tid + i * 256;
        int r = l >> 4, c8 = (l & 15) << 3;
        *(uint4*)&Bk[r][c8] = *(const uint4*)(wkb + (size_t)r * DD + c8);
        *(uint4*)&Bv[r][c8] = *(const uint4*)(wvb + (size_t)r * DD + c8);
    }
    __syncthreads();

    const int wid = tid >> 6, lane = tid & 63;
    const int wm = (wid & 1) * 32, wn = (wid >> 1) * 64;
    const int lr = lane & 15, lk = (lane >> 4) << 3;
    f32x4 ak[2][4] = {}, av[2][4] = {};
    #pragma unroll
    for (int ks = 0; ks < 4; ++ks) {
        int kk = ks * 32 + lk;
        bf16x8 aL[2], aR[2];
        #pragma unroll
        for (int mi = 0; mi < 2; ++mi) {
            aL[mi] = *(const bf16x8*)&Aln[wm + mi * 16 + lr][kk];
            aR[mi] = *(const bf16x8*)&Araw[wm + mi * 16 + lr][kk];
        }
        #pragma unroll
        for (int ni = 0; ni < 4; ++ni) {
            bf16x8 bK = *(const bf16x8*)&Bk[wn + ni * 16 + lr][kk];
            bf16x8 bV = *(const bf16x8*)&Bv[wn + ni * 16 + lr][kk];
            #pragma unroll
            for (int mi = 0; mi < 2; ++mi) {
                ak[mi][ni] = __builtin_amdgcn_mfma_f32_16x16x32_bf16(aL[mi], bK, ak[mi][ni], 0, 0, 0);
                av[mi][ni] = __builtin_amdgcn_mfma_f32_16x16x32_bf16(aR[mi], bV, av[mi][ni], 0, 0, 0);
            }
        }
    }
    #pragma unroll
    for (int mi = 0; mi < 2; ++mi) {
        #pragma unroll
        for (int ni = 0; ni < 4; ++ni) {
            int n = wn + ni * 16 + (lane & 15);
            #pragma unroll
            for (int r = 0; r < 4; ++r) {
                int m = row0 + wm + mi * 16 + ((lane >> 4) << 2) + r;
                int b = m >> 12, pix = m & 4095;
                int iy = pix >> 6, ix = pix & 63;
                int h = ((iy & 1) << 1) | (ix & 1);
                int cp = ((iy >> 1) << 5) | (ix >> 1);
                size_t orow = ((size_t)(b * 4 + h) << 10) + cp;
                kbuf[orow * DD + n] = f2bf(ak[mi][ni][r]);
                vbuf[orow * DD + n] = f2bf(av[mi][ni][r]);
            }
        }
    }
}

// ---------------------------------------------------------------------------
// conv GEMM (im2col gather, K=1152) + LN epilogue -> xout fp32.
// BM=64, BN=128 (full N). 4 waves 2Mx2N (32x64).
// ---------------------------------------------------------------------------
__global__ __launch_bounds__(256)
void conv_ln_kernel(const float* __restrict__ x, const ushort* __restrict__ wcb,
                    const float* __restrict__ lg_, const float* __restrict__ lb_,
                    float* __restrict__ xout)
{
    __shared__ ushort As[64][72];
    __shared__ ushort Bs[128][72];
    __shared__ float  es[64][132];
    __shared__ float  rstat[64][2];
    const int tid = threadIdx.x, wid = tid >> 6, lane = tid & 63;
    const int row0 = blockIdx.x * 64;
    const int wm = (wid & 1) * 32, wn = (wid >> 1) * 64;
    const int lr = lane & 15, lk = (lane >> 4) << 3;
    f32x4 acc[2][4] = {};

    for (int k0 = 0; k0 < 1152; k0 += 64) {
        #pragma unroll
        for (int i = 0; i < 4; ++i) {           // A gather: 1024 float4
            int l = tid + i * 256;
            int r = l >> 4, c4 = (l & 15) << 2;
            int m = row0 + r;
            int b = m >> 10, p = m & 1023;
            int y = p >> 5, xx = p & 31;
            int kg = k0 + c4;
            int tap = kg >> 7, di = kg & 127;
            int ky = tap / 3, kx = tap - ky * 3;
            int iy = 2 * y + ky - 1, ix = 2 * xx + kx - 1;
            float4 v;
            if ((unsigned)iy < (unsigned)HI_ && (unsigned)ix < (unsigned)WI_)
                v = *(const float4*)(x + ((size_t)b * NIN + iy * WI_ + ix) * DD + di);
            else v = make_float4(0.f, 0.f, 0.f, 0.f);
            ushort4 o; o.x = f2bf(v.x); o.y = f2bf(v.y); o.z = f2bf(v.z); o.w = f2bf(v.w);
            *(ushort4*)&As[r][c4] = o;
        }
        #pragma unroll
        for (int i = 0; i < 4; ++i) {           // B: 1024 uint4
            int l = tid + i * 256;
            int r = l >> 3, c8 = (l & 7) << 3;
            *(uint4*)&Bs[r][c8] = *(const uint4*)(wcb + (size_t)r * 1152 + k0 + c8);
        }
        __syncthreads();
        #pragma unroll
        for (int ks = 0; ks < 2; ++ks) {
            int kk = ks * 32 + lk;
            bf16x8 aF[2];
            aF[0] = *(const bf16x8*)&As[wm + lr][kk];
            aF[1] = *(const bf16x8*)&As[wm + 16 + lr][kk];
            #pragma unroll
            for (int ni = 0; ni < 4; ++ni) {
                bf16x8 bF = *(const bf16x8*)&Bs[wn + ni * 16 + lr][kk];
                acc[0][ni] = __builtin_amdgcn_mfma_f32_16x16x32_bf16(aF[0], bF, acc[0][ni], 0, 0, 0);
                acc[1][ni] = __builtin_amdgcn_mfma_f32_16x16x32_bf16(aF[1], bF, acc[1][ni], 0, 0, 0);
            }
        }
        __syncthreads();
    }
    #pragma unroll
    for (int mi = 0; mi < 2; ++mi)
        #pragma unroll
        for (int ni = 0; ni < 4; ++ni) {
            int n = wn + ni * 16 + (lane & 15);
            #pragma unroll
            for (int r = 0; r < 4; ++r)
                es[wm + mi * 16 + ((lane >> 4) << 2) + r][n] = acc[mi][ni][r];
        }
    __syncthreads();
    {   // row stats
        int r = tid >> 2, q = tid & 3;
        float s = 0.f, s2 = 0.f;
        #pragma unroll
        for (int c = 0; c < 32; ++c) { float v = es[r][q * 32 + c]; s += v; s2 += v * v; }
        s += __shfl_down(s, 1, 64); s2 += __shfl_down(s2, 1, 64);
        s += __shfl_down(s, 2, 64); s2 += __shfl_down(s2, 2, 64);
        if (q == 0) {
            float mu = s * (1.f / DD);
            float var = s2 * (1.f / DD) - mu * mu;
            rstat[r][0] = mu; rstat[r][1] = rsqrtf(var + LN_EPS);
        }
    }
    __syncthreads();
    #pragma unroll
    for (int i = 0; i < 8; ++i) {
        int l = tid + i * 256;
        int r = l >> 5, c4 = (l & 31) << 2;
        float mu = rstat[r][0], rs = rstat[r][1];
        float4 o;
        o.x = (es[r][c4 + 0] - mu) * rs * lg_[c4 + 0] + lb_[c4 + 0];
        o.y = (es[r][c4 + 1] - mu) * rs * lg_[c4 + 1] + lb_[c4 + 1];
        o.z = (es[r][c4 + 2] - mu) * rs * lg_[c4 + 2] + lb_[c4 + 2];
        o.w = (es[r][c4 + 3] - mu) * rs * lg_[c4 + 3] + lb_[c4 + 3];
        *(float4*)(xout + (size_t)(row0 + r) * DD + c4) = o;
    }
}

// ---------------------------------------------------------------------------
// q = LN(xout) @ wq^T  (bf16 out). BM=64, BN=128 full, K=128 single-shot.
// ---------------------------------------------------------------------------
__global__ __launch_bounds__(256)
void qln_gemm_kernel(const float* __restrict__ xout, const ushort* __restrict__ wqb,
                     const float* __restrict__ lg_, const float* __restrict__ lb_,
                     ushort* __restrict__ q)
{
    __shared__ float  xs[64][132];
    __shared__ ushort As[64][136];
    __shared__ ushort Bs[128][136];
    __shared__ float  rstat[64][2];
    const int tid = threadIdx.x, wid = tid >> 6, lane = tid & 63;
    const int row0 = blockIdx.x * 64;
    const int wm = (wid & 1) * 32, wn = (wid >> 1) * 64;
    const int lr = lane & 15, lk = (lane >> 4) << 3;

    #pragma unroll
    for (int i = 0; i < 8; ++i) {
        int l = tid + i * 256;
        int r = l >> 5, c4 = (l & 31) << 2;
        *(float4*)&xs[r][c4] = *(const float4*)(xout + (size_t)(row0 + r) * DD + c4);
    }
    __syncthreads();
    {
        int r = tid >> 2, qq = tid & 3;
        float s = 0.f, s2 = 0.f;
        #pragma unroll
        for (int c = 0; c < 32; ++c) { float v = xs[r][qq * 32 + c]; s += v; s2 += v * v; }
        s += __shfl_down(s, 1, 64); s2 += __shfl_down(s2, 1, 64);
        s += __shfl_down(s, 2, 64); s2 += __shfl_down(s2, 2, 64);
        if (qq == 0) {
            float mu = s * (1.f / DD);
            float var = s2 * (1.f / DD) - mu * mu;
            rstat[r][0] = mu; rstat[r][1] = rsqrtf(var + LN_EPS);
        }
    }
    __syncthreads();
    #pragma unroll
    for (int i = 0; i < 8; ++i) {
        int l = tid + i * 256;
        int r = l >> 5, c4 = (l & 31) << 2;
        float mu = rstat[r][0], rs = rstat[r][1];
        ushort4 o;
        o.x = f2bf((xs[r][c4 + 0] - mu) * rs * lg_[c4 + 0] + lb_[c4 + 0]);
        o.y = f2bf((xs[r][c4 + 1] - mu) * rs * lg_[c4 + 1] + lb_[c4 + 1]);
        o.z = f2bf((xs[r][c4 + 2] - mu) * rs * lg_[c4 + 2] + lb_[c4 + 2]);
        o.w = f2bf((xs[r][c4 + 3] - mu) * rs * lg_[c4 + 3] + lb_[c4 + 3]);
        *(ushort4*)&As[r][c4] = o;
    }
    #pragma unroll
    for (int i = 0; i < 8; ++i) {
        int l = tid + i * 256;
        int r = l >> 4, c8 = (l & 15) << 3;
        *(uint4*)&Bs[r][c8] = *(const uint4*)(wqb + (size_t)r * DD + c8);
    }
    __syncthreads();
    f32x4 acc[2][4] = {};
    #pragma unroll
    for (int ks = 0; ks < 4; ++ks) {
        int kk = ks * 32 + lk;
        bf16x8 aF[2];
        aF[0] = *(const bf16x8*)&As[wm + lr][kk];
        aF[1] = *(const bf16x8*)&As[wm + 16 + lr][kk];
        #pragma unroll
        for (int ni = 0; ni < 4; ++ni) {
            bf16x8 bF = *(const bf16x8*)&Bs[wn + ni * 16 + lr][kk];
            acc[0][ni] = __builtin_amdgcn_mfma_f32_16x16x32_bf16(aF[0], bF, acc[0][ni], 0, 0, 0);
            acc[1][ni] = __builtin_amdgcn_mfma_f32_16x16x32_bf16(aF[1], bF, acc[1][ni], 0, 0, 0);
        }
    }
    #pragma unroll
    for (int mi = 0; mi < 2; ++mi)
        #pragma unroll
        for (int ni = 0; ni < 4; ++ni) {
            int n = wn + ni * 16 + (lane & 15);
            #pragma unroll
            for (int r = 0; r < 4; ++r) {
                int m = row0 + wm + mi * 16 + ((lane >> 4) << 2) + r;
                q[(size_t)m * DD + n] = f2bf(acc[mi][ni][r]);
            }
        }
}

// ---------------------------------------------------------------------------
// Fused attention: logits + softmax(+EPS) + gather(invalid->sm0) + denom +
// AV update. One block per (b, cy): 32 positions x 4 heads.
// Writes gbuf, denb, xout +=.
// ---------------------------------------------------------------------------
__global__ __launch_bounds__(256)
void attnupd_kernel(const ushort* __restrict__ q, const ushort* __restrict__ kbuf,
                    const ushort* __restrict__ vbuf, const float* __restrict__ rpb,
                    const float* __restrict__ tau, float* __restrict__ xout,
                    float* __restrict__ gbuf, float* __restrict__ denb)
{
    const int bcy = blockIdx.x;
    const int b = bcy >> 5, cy = bcy & 31;
    const int ry0 = min(max(cy - 1, 0), HO_ - 3);
    __shared__ ushort kv[4][3][32][136];
    __shared__ ushort qs[32][136];
    __shared__ ushort k0s[4][9][128];
    __shared__ ushort q0s[128];
    __shared__ float  lg[32][36];
    __shared__ float  lg0[40];
    __shared__ float  sm0[4];
    __shared__ float  den[32];
    __shared__ float  hsum[32][4];
    const int tid = threadIdx.x;

    // q tile (32x128 bf16 = 512 uint4)
    #pragma unroll
    for (int i = 0; i < 2; ++i) {
        int l = tid + i * 256;
        int c = l >> 4, d8 = (l & 15) << 3;
        *(uint4*)&qs[c][d8] = *(const uint4*)(q + ((size_t)(b * NOUT + cy * 32 + c)) * DD + d8);
    }
    if (tid < 16)
        *(uint4*)&q0s[tid * 8] = *(const uint4*)(q + (size_t)(b * NOUT) * DD + tid * 8);
    // k tile: 4h x 3r x 32c x 128d = 6144 uint4
    #pragma unroll
    for (int i = 0; i < 24; ++i) {
        int l = tid + i * 256;
        int h = l / 1536, l2 = l - h * 1536;
        int rc = l2 >> 4, d8 = (l2 & 15) << 3;
        int r = rc >> 5, c = rc & 31;
        *(uint4*)&kv[h][r][c][d8] =
            *(const uint4*)(kbuf + (((size_t)(b * 4 + h) << 10) + (ry0 + r) * 32 + c) * DD + d8);
    }
    // p=0 window: rows 0..2, cols 0..2 (576 uint4)
    for (int l = tid; l < 576; l += 256) {
        int row = l >> 4, d8 = (l & 15) << 3;
        int h = row / 9, jj = row - h * 9;
        int ky = jj / 3, kx = jj - ky * 3;
        *(uint4*)&k0s[h][jj][d8] =
            *(const uint4*)(kbuf + (((size_t)(b * 4 + h) << 10) + ky * 32 + kx) * DD + d8);
    }
    __syncthreads();

    // phase A: 1152 tile dots + 36 p0 dots
    for (int task = tid; task < 1188; task += 256) {
        const ushort *kp, *qp;
        int c = 0, h, jj;
        if (task < 1152) {
            c = task / 36; int t2 = task - c * 36;
            h = t2 / 9; jj = t2 - h * 9;
            int ky = jj / 3, kx = jj - ky * 3;
            int nx = min(max(c - 1, 0), WO_ - 3) + kx;
            kp = &kv[h][ky][nx][0]; qp = &qs[c][0];
        } else {
            int t2 = task - 1152;
            h = t2 / 9; jj = t2 - h * 9;
            kp = &k0s[h][jj][0]; qp = q0s;
        }
        float s = 0.f;
        #pragma unroll 4
        for (int d = 0; d < 128; d += 8) {
            uint4 ku = *(const uint4*)(kp + d);
            uint4 qu = *(const uint4*)(qp + d);
            const ushort* kk2 = (const ushort*)&ku;
            const ushort* qq2 = (const ushort*)&qu;
            #pragma unroll
            for (int t = 0; t < 8; ++t) s += bf2f(kk2[t]) * bf2f(qq2[t]);
        }
        if (task < 1152) lg[c][h * 9 + jj] = s;
        else             lg0[task - 1152] = s;
    }
    __syncthreads();

    // softmax (+EPS): 128 (c,h) groups + 4 p0 groups
    if (tid < 132) {
        float scale = expf(tau[0]);
        int h; const float* lptr; int c = 0;
        if (tid < 128) { c = tid >> 2; h = tid & 3; lptr = &lg[c][h * 9]; }
        else           { h = tid - 128; lptr = &lg0[h * 9]; }
        float tmpv[9], mx = -1e30f;
        #pragma unroll
        for (int jj = 0; jj < 9; ++jj) {
            float v = (lptr[jj] + rpb[h * 9 + jj]) * scale;
            tmpv[jj] = v; mx = fmaxf(mx, v);
        }
        float ss = 0.f;
        #pragma unroll
        for (int jj = 0; jj < 9; ++jj) { tmpv[jj] = expf(tmpv[jj] - mx); ss += tmpv[jj]; }
        float inv = 1.f / ss;
        if (tid < 128) {
            #pragma unroll
            for (int jj = 0; jj < 9; ++jj) lg[c][h * 9 + jj] = tmpv[jj] * inv + ATT_EPS;
        } else sm0[h] = tmpv[0] * inv + ATT_EPS;
    }
    __syncthreads();

    // gather -> gbuf, head-sums
    if (tid < 128) {
        int c = tid >> 2, h = tid & 3;
        float s = 0.f, gv[9];
        #pragma unroll
        for (int jj = 0; jj < 9; ++jj) {
            int dy = jj / 3 - 1, dx = jj % 3 - 1;
            bool valid = ((unsigned)(cy + dy) < (unsigned)HO_) && ((unsigned)(c + dx) < (unsigned)WO_);
            float v = valid ? lg[c][h * 9 + jj] : sm0[h];
            gv[jj] = v; s += v;
        }
        float* gp = gbuf + (((size_t)(b * 4 + h) << 10) + cy * 32 + c) * 9;
        #pragma unroll
        for (int jj = 0; jj < 9; ++jj) { gp[jj] = gv[jj]; lg[c][h * 9 + jj] = gv[jj]; }
        hsum[c][h] = s;
    }
    __syncthreads();
    if (tid < 32) {
        float dd = 4.f * (hsum[tid][0] + hsum[tid][1] + hsum[tid][2] + hsum[tid][3]) + ATT_EPS;
        den[tid] = 1.f / dd;
        denb[b * NOUT + cy * 32 + tid] = dd;
    }
    __syncthreads();
    if (tid < 128) {
        int c = tid >> 2, h = tid & 3;
        float inv = den[c];
        #pragma unroll
        for (int jj = 0; jj < 9; ++jj) lg[c][h * 9 + jj] *= inv;   // coeff
    }
    __syncthreads();

    // phase B: load v into kv
    #pragma unroll
    for (int i = 0; i < 24; ++i) {
        int l = tid + i * 256;
        int h = l / 1536, l2 = l - h * 1536;
        int rc = l2 >> 4, d8 = (l2 & 15) << 3;
        int r = rc >> 5, c = rc & 31;
        *(uint4*)&kv[h][r][c][d8] =
            *(const uint4*)(vbuf + (((size_t)(b * 4 + h) << 10) + (ry0 + r) * 32 + c) * DD + d8);
    }
    __syncthreads();

    // update: thread -> (c = tid>>3, 16 d's)
    {
        int c = tid >> 3, d0 = (tid & 7) << 4;
        int rx0 = min(max(c - 1, 0), WO_ - 3);
        float acc[16] = {};
        #pragma unroll
        for (int h = 0; h < 4; ++h)
            #pragma unroll
            for (int jj = 0; jj < 9; ++jj) {
                float cf = lg[c][h * 9 + jj];
                int ky = jj / 3, kx = jj - ky * 3;
                const ushort* vp = &kv[h][ky][rx0 + kx][d0];
                uint4 v0 = *(const uint4*)(vp);
                uint4 v1 = *(const uint4*)(vp + 8);
                const ushort* vs0 = (const ushort*)&v0;
                const ushort* vs1 = (const ushort*)&v1;
                #pragma unroll
                for (int t = 0; t < 8; ++t) {
                    acc[t]     += cf * bf2f(vs0[t]);
                    acc[t + 8] += cf * bf2f(vs1[t]);
                }
            }
        float* xp = xout + ((size_t)(b * NOUT + cy * 32 + c)) * DD + d0;
        #pragma unroll
        for (int t = 0; t < 16; t += 4) {
            float4 o = *(float4*)(xp + t);
            o.x += acc[t]; o.y += acc[t + 1]; o.z += acc[t + 2]; o.w += acc[t + 3];
            *(float4*)(xp + t) = o;
        }
    }
}

// ---------------------------------------------------------------------------
// FFN1: h1 = gelu(xout @ w1^T + b1), bf16 out. BM=32, BN=256 full, K=128.
// 4 waves 2Mx2N (16x128 each).
// ---------------------------------------------------------------------------
__global__ __launch_bounds__(256)
void ffn1_kernel(const float* __restrict__ xout, const ushort* __restrict__ w1b,
                 const float* __restrict__ b1, ushort* __restrict__ h1)
{
    __shared__ ushort As[32][136];
    __shared__ ushort Bs[256][136];
    const int tid = threadIdx.x, wid = tid >> 6, lane = tid & 63;
    const int row0 = blockIdx.x * 32;
    const int wm = (wid & 1) * 16, wn = (wid >> 1) * 128;
    const int lr = lane & 15, lk = (lane >> 4) << 3;

    #pragma unroll
    for (int i = 0; i < 4; ++i) {               // A: 1024 float4
        int l = tid + i * 256;
        int r = l >> 5, c4 = (l & 31) << 2;
        float4 v = *(const float4*)(xout + (size_t)(row0 + r) * DD + c4);
        ushort4 o; o.x = f2bf(v.x); o.y = f2bf(v.y); o.z = f2bf(v.z); o.w = f2bf(v.w);
        *(ushort4*)&As[r][c4] = o;
    }
    #pragma unroll
    for (int i = 0; i < 16; ++i) {              // B: 4096 uint4
        int l = tid + i * 256;
        int r = l >> 4, c8 = (l & 15) << 3;
        *(uint4*)&Bs[r][c8] = *(const uint4*)(w1b + (size_t)r * DD + c8);
    }
    __syncthreads();
    f32x4 acc[8] = {};
    #pragma unroll
    for (int ks = 0; ks < 4; ++ks) {
        int kk = ks * 32 + lk;
        bf16x8 a0 = *(const bf16x8*)&As[wm + lr][kk];
        #pragma unroll
        for (int ni = 0; ni < 8; ++ni) {
            bf16x8 bF = *(const bf16x8*)&Bs[wn + ni * 16 + lr][kk];
            acc[ni] = __builtin_amdgcn_mfma_f32_16x16x32_bf16(a0, bF, acc[ni], 0, 0, 0);
        }
    }
    #pragma unroll
    for (int ni = 0; ni < 8; ++ni) {
        int n = wn + ni * 16 + (lane & 15);
        float bv = b1[n];
        #pragma unroll
        for (int r = 0; r < 4; ++r) {
            int m = row0 + wm + ((lane >> 4) << 2) + r;
            float v = acc[ni][r] + bv;
            v = 0.5f * v * (1.f + erff(v * 0.70710678118654752f));
            h1[(size_t)m * 256 + n] = f2bf(v);
        }
    }
}

// ---------------------------------------------------------------------------
// FFN2: xout += LN(h1 @ w2^T + b2). BM=32, BN=128 full, K=256.
// LAST: also write final x_out to d_out.
// ---------------------------------------------------------------------------
template<int LAST>
__global__ __launch_bounds__(256)
void ffn2_kernel(const ushort* __restrict__ h1, const ushort* __restrict__ w2b,
                 const float* __restrict__ b2, const float* __restrict__ lg_,
                 const float* __restrict__ lb_, float* __restrict__ xout,
                 float* __restrict__ out)
{
    __shared__ ushort As[32][264];
    __shared__ ushort Bs[128][264];
    __shared__ float  es[32][132];
    __shared__ float  rstat[32][2];
    const int tid = threadIdx.x, wid = tid >> 6, lane = tid & 63;
    const int row0 = blockIdx.x * 32;
    const int wm = (wid & 1) * 16, wn = (wid >> 1) * 64;
    const int lr = lane & 15, lk = (lane >> 4) << 3;

    #pragma unroll
    for (int i = 0; i < 4; ++i) {               // A: 1024 uint4
        int l = tid + i * 256;
        int r = l >> 5, c8 = (l & 31) << 3;
        *(uint4*)&As[r][c8] = *(const uint4*)(h1 + (size_t)(row0 + r) * 256 + c8);
    }
    #pragma unroll
    for (int i = 0; i < 16; ++i) {              // B: 4096 uint4
        int l = tid + i * 256;
        int r = l >> 5, c8 = (l & 31) << 3;
        *(uint4*)&Bs[r][c8] = *(const uint4*)(w2b + (size_t)r * 256 + c8);
    }
    __syncthreads();
    f32x4 acc[4] = {};
    #pragma unroll
    for (int ks = 0; ks < 8; ++ks) {
        int kk = ks * 32 + lk;
        bf16x8 a0 = *(const bf16x8*)&As[wm + lr][kk];
        #pragma unroll
        for (int ni = 0; ni < 4; ++ni) {
            bf16x8 bF = *(const bf16x8*)&Bs[wn + ni * 16 + lr][kk];
            acc[ni] = __builtin_amdgcn_mfma_f32_16x16x32_bf16(a0, bF, acc[ni], 0, 0, 0);
        }
    }
    #pragma unroll
    for (int ni = 0; ni < 4; ++ni) {
        int n = wn + ni * 16 + (lane & 15);
        float bv = b2[n];
        #pragma unroll
        for (int r = 0; r < 4; ++r)
            es[wm + ((lane >> 4) << 2) + r][n] = acc[ni][r] + bv;
    }
    __syncthreads();
    {   // row stats: 8 threads/row
        int r = tid >> 3, qq = tid & 7;
        float s = 0.f, s2 = 0.f;
        #pragma unroll
        for (int c = 0; c < 16; ++c) { float v = es[r][qq * 16 + c]; s += v; s2 += v * v; }
        s += __shfl_down(s, 1, 64); s2 += __shfl_down(s2, 1, 64);
        s += __shfl_down(s, 2, 64); s2 += __shfl_down(s2, 2, 64);
        s += __shfl_down(s, 4, 64); s2 += __shfl_down(s2, 4, 64);
        if (qq == 0) {
            float mu = s * (1.f / DD);
            float var = s2 * (1.f / DD) - mu * mu;
            rstat[r][0] = mu; rstat[r][1] = rsqrtf(var + LN_EPS);
        }
    }
    __syncthreads();
    #pragma unroll
    for (int i = 0; i < 4; ++i) {
        int l = tid + i * 256;
        int r = l >> 5, c4 = (l & 31) << 2;
        float mu = rstat[r][0], rs = rstat[r][1];
        size_t off = (size_t)(row0 + r) * DD + c4;
        float4 xo = *(const float4*)(xout + off);
        float4 o;
        o.x = xo.x + (es[r][c4 + 0] - mu) * rs * lg_[c4 + 0] + lb_[c4 + 0];
        o.y = xo.y + (es[r][c4 + 1] - mu) * rs * lg_[c4 + 1] + lb_[c4 + 1];
        o.z = xo.z + (es[r][c4 + 2] - mu) * rs * lg_[c4 + 2] + lb_[c4 + 2];
        o.w = xo.w + (es[r][c4 + 3] - mu) * rs * lg_[c4 + 3] + lb_[c4 + 3];
        *(float4*)(xout + off) = o;
        if (LAST) *(float4*)(out + off) = o;
    }
}

// ---------------------------------------------------------------------------
// A_row (blocks 0..32767) and A_col incl. dump (blocks 32768..65535).
// ---------------------------------------------------------------------------
__global__ __launch_bounds__(256)
void arowcol_kernel(const float* __restrict__ gbuf, const float* __restrict__ denb,
                    float* __restrict__ Arow, float* __restrict__ Acol)
{
    const int tid = threadIdx.x;
    __shared__ int   cols[9];
    __shared__ float vals[9];
    __shared__ float wred[9][4];
    if (blockIdx.x < 32768) {
        const int bi = blockIdx.x;
        const int b = bi >> 12, i = bi & 4095;
        const int h = i >> 10, p = i & 1023;
        const int cy = p >> 5, cx = p & 31;
        if (tid < 9) {
            int dy = tid / 3 - 1, dx = tid % 3 - 1;
            bool valid = ((unsigned)(cy + dy) < (unsigned)HO_) && ((unsigned)(cx + dx) < (unsigned)WO_);
            cols[tid] = valid ? (cy + dy) * WO_ + (cx + dx) : 0;
            vals[tid] = 4.f * gbuf[(((size_t)(b * 4 + h) << 10) + p) * 9 + tid];
        }
        __syncthreads();
        float* row = Arow + (size_t)bi * NOUT;
        #pragma unroll
        for (int cc = 0; cc < 4; ++cc) {
            int c = cc * 256 + tid;
            float acc = 0.f;
            #pragma unroll
            for (int jj = 0; jj < 9; ++jj)
                if (cols[jj] == c) acc += vals[jj];
            row[c] = acc;
        }
    } else {
        const int br = blockIdx.x - 32768;
        const int b = br >> 12, r = br & 4095;
        const int h = r & 3, coarse = r >> 2;
        const int cy = coarse >> 5, cx = coarse & 31;
        if (tid < 9) {
            int dy = tid / 3 - 1, dx = tid % 3 - 1;
            int py = cy - dy, px = cx - dx;
            float v = 0.f;
            if ((unsigned)py < (unsigned)HO_ && (unsigned)px < (unsigned)WO_) {
                int p = py * WO_ + px;
                v = gbuf[(((size_t)(b * 4 + h) << 10) + p) * 9 + tid] / denb[b * NOUT + p];
            }
            vals[tid] = v;
        }
        if (r == 0) {
            float part[9] = {};
            for (int p = tid; p < NOUT; p += 256) {
                float invd = 1.f / denb[b * NOUT + p];
                int py = p >> 5, px = p & 31;
                #pragma unroll
                for (int jj = 0; jj < 9; ++jj) {
                    int dy = jj / 3 - 1, dx = jj % 3 - 1;
                    bool valid = ((unsigned)(py + dy) < (unsigned)HO_) && ((unsigned)(px + dx) < (unsigned)WO_);
                    if (!valid) part[jj] += invd;
                }
            }
            #pragma unroll
            for (int jj = 0; jj < 9; ++jj) {
                float s = part[jj];
                #pragma unroll
                for (int o = 32; o > 0; o >>= 1) s += __shfl_down(s, o, 64);
                if ((tid & 63) == 0) wred[jj][tid >> 6] = s;
            }
            __syncthreads();
            if (tid < 9) {
                float s = wred[tid][0] + wred[tid][1] + wred[tid][2] + wred[tid][3];
                float H = 0.f;
                for (int h2 = 0; h2 < 4; ++h2)
                    H += gbuf[(((size_t)(b * 4 + h2)) << 10) * 9];
                vals[tid] += H * s;
            }
        }
        __syncthreads();
        float* row = Acol + (size_t)br * NOUT;
        #pragma unroll
        for (int cc = 0; cc < 4; ++cc) {
            int c = cc * 256 + tid;
            row[c] = (c < 36) ? vals[c % 9] : 0.f;
        }
    }
}

// ---------------------------------------------------------------------------
extern "C" void kernel_launch(void* const* d_in, const int* in_sizes, int n_in,
                              void* d_out, int out_size, void* d_ws, size_t ws_size,
                              hipStream_t stream)
{
    const float* x        = (const float*)d_in[0];
    const float* seed_w   = (const float*)d_in[1];
    const float* wq       = (const float*)d_in[2];
    const float* wk       = (const float*)d_in[3];
    const float* wv       = (const float*)d_in[4];
    const float* w1       = (const float*)d_in[5];
    const float* b1       = (const float*)d_in[6];
    const float* w2       = (const float*)d_in[7];
    const float* b2       = (const float*)d_in[8];
    const float* ln_in_g  = (const float*)d_in[9];
    const float* ln_in_b  = (const float*)d_in[10];
    const float* ln_out_g = (const float*)d_in[11];
    const float* ln_out_b = (const float*)d_in[12];
    const float* rpb      = (const float*)d_in[13];
    const float* tau      = (const float*)d_in[14];

    float* out  = (float*)d_out;
    float* Arow = out + (size_t)BB * NOUT * DD;        // 1,048,576
    float* Acol = Arow + (size_t)BB * NIN * NOUT;      // +33,554,432

    // Must-survive scratch in d_ws (~5.9 MB):
    float* ws    = (float*)d_ws;
    float* xout  = ws;                                 // 1,048,576
    float* gbuf  = xout + (size_t)BB * NOUT * DD;      // 294,912
    float* denb  = gbuf + (size_t)BB * 4 * NOUT * 9;   // 8,192
    ushort* wb   = (ushort*)(denb + BB * NOUT);        // 262,144 ushorts
    ushort* wkb  = wb;
    ushort* wvb  = wb + 16384;
    ushort* wqb  = wb + 32768;
    ushort* w1b  = wb + 49152;
    ushort* w2b  = wb + 81920;
    ushort* wcb  = wb + 114688;

    // Dead-by-the-end scratch carved from the A_row output region (134 MB):
    // kbuf/vbuf: BB*4*1024*128 = 4,194,304 bf16 each; qb 1M; h1 2M.
    ushort* kbuf = (ushort*)Arow;
    ushort* vbuf = kbuf + (size_t)4194304;
    ushort* qb   = vbuf + (size_t)4194304;
    ushort* h1   = qb   + (size_t)1048576;
    // total 11,534,336 ushorts = 23 MB < 134 MB

    // --- preamble ---
    wconvert_kernel<<<1024, 256, 0, stream>>>(wq, wk, wv, w1, w2, seed_w, wb);
    prep_kv_kernel<<<BB * NIN / 64, 256, 0, stream>>>(x, wkb, wvb, ln_in_g, ln_in_b,
                                                      kbuf, vbuf);
    conv_ln_kernel<<<BB * NOUT / 64, 256, 0, stream>>>(x, wcb, ln_out_g, ln_out_b, xout);

    // --- 3 iterations ---
    for (int it = 0; it < 3; ++it) {
        qln_gemm_kernel<<<BB * NOUT / 64, 256, 0, stream>>>(xout, wqb, ln_out_g, ln_out_b, qb);
        attnupd_kernel<<<BB * HO_, 256, 0, stream>>>(qb, kbuf, vbuf, rpb, tau,
                                                     xout, gbuf, denb);
        ffn1_kernel<<<BB * NOUT / 32, 256, 0, stream>>>(xout, w1b, b1, h1);
        if (it < 2)
            ffn2_kernel<0><<<BB * NOUT / 32, 256, 0, stream>>>(h1, w2b, b2, ln_out_g,
                                                               ln_out_b, xout, out);
        else
            ffn2_kernel<1><<<BB * NOUT / 32, 256, 0, stream>>>(h1, w2b, b2, ln_out_g,
                                                               ln_out_b, xout, out);
    }

    // --- epilogue: A_row + A_col (+dump inline) ---
    arowcol_kernel<<<2 * BB * NIN, 256, 0, stream>>>(gbuf, denb, Arow, Acol);
}